// Round 2
// baseline (88.014 us; speedup 1.0000x reference)
//
#include <hip/hip_runtime.h>
#include <hip/hip_bf16.h>
#include <math.h>

#define B_ROWS 4096
#define N_ROWS 8192
#define D_DIM  128
// (1/T) * log2(e) = 2 * 1.4426950408889634
#define SCALE_LOG2 2.8853900817779268f

#define CSPLIT 32
#define CHUNK (N_ROWS / CSPLIT)        // 256 cols per block
#define TILES_PER_CHUNK (CHUNK / 32)   // 8 column tiles

typedef __bf16 bf16x8 __attribute__((ext_vector_type(8)));
typedef __bf16 bf16x2 __attribute__((ext_vector_type(2)));
typedef float  f32x16 __attribute__((ext_vector_type(16)));

#if __has_builtin(__builtin_amdgcn_exp2f)
#define EXP2F(x) __builtin_amdgcn_exp2f(x)
#else
#define EXP2F(x) exp2f(x)
#endif

// ---------- K1: normalize rows of concat(z_i, z_j) -> bf16 zn ----------
// one wave per row; 4 rows per 256-thread block
__global__ __launch_bounds__(256) void k_normalize(const float* __restrict__ zi,
                                                   const float* __restrict__ zj,
                                                   __bf16* __restrict__ zn) {
    const int wid  = threadIdx.x >> 6;
    const int lane = threadIdx.x & 63;
    const int row  = blockIdx.x * 4 + wid;
    const float* src = (row < B_ROWS) ? (zi + (size_t)row * D_DIM)
                                      : (zj + (size_t)(row - B_ROWS) * D_DIM);
    float2 v = ((const float2*)src)[lane];
    float ss = v.x * v.x + v.y * v.y;
    #pragma unroll
    for (int off = 1; off < 64; off <<= 1) ss += __shfl_xor(ss, off, 64);
    float inv = 1.0f / fmaxf(sqrtf(ss), 1e-8f);
    bf16x2 o;
    o[0] = (__bf16)(v.x * inv);
    o[1] = (__bf16)(v.y * inv);
    ((bf16x2*)zn)[(size_t)row * 64 + lane] = o;
}

// ---------- K2: NT-GEMM (zn . zn^T) with fused exp2 row-sum ----------
// block = 4 waves; wave w owns rows [rb*128 + w*32, +32); all waves stream the
// same 256-column chunk (cs). No LDS: whole zn (2 MB) is L2-resident, and the
// 4KB B-tile is shared across the block's 4 waves via L1.
// CSPLIT=32 -> 2048 blocks -> 32 waves/CU (full occupancy at VGPR<=64): the
// per-tile {8 L2 loads -> 8-deep MFMA chain -> 16 exp2} latency chain is
// hidden by TLP, not by register pipelining (keeps VGPR low).
__global__ __launch_bounds__(256) void k_gemm_expsum(const __bf16* __restrict__ zn,
                                                     float* __restrict__ partials) {
    const int rb   = blockIdx.x;   // 0..63 row-block
    const int cs   = blockIdx.y;   // 0..31 column split
    const int wid  = threadIdx.x >> 6;
    const int lane = threadIdx.x & 63;
    const int h    = lane >> 5;    // lane half (k-group)
    const int ln   = lane & 31;

    const int row0 = rb * 128 + wid * 32;
    const bf16x8* zn8 = (const bf16x8*)zn;   // 16 groups of 8 bf16 per row

    // A fragments: lane ln supplies row (row0+ln), k = kk*16 + h*8 .. +7
    bf16x8 a[8];
    #pragma unroll
    for (int kk = 0; kk < 8; ++kk)
        a[kk] = zn8[(size_t)(row0 + ln) * 16 + kk * 2 + h];

    float sums[16];
    #pragma unroll
    for (int i = 0; i < 16; ++i) sums[i] = 0.0f;

    const int col_base = cs * CHUNK;
    for (int ct = 0; ct < TILES_PER_CHUNK; ++ct) {
        const int c0 = col_base + ct * 32;
        bf16x8 b[8];
        #pragma unroll
        for (int kk = 0; kk < 8; ++kk)
            b[kk] = zn8[(size_t)(c0 + ln) * 16 + kk * 2 + h];
        f32x16 acc = {};
        #pragma unroll
        for (int kk = 0; kk < 8; ++kk)
            acc = __builtin_amdgcn_mfma_f32_32x32x16_bf16(a[kk], b[kk], acc, 0, 0, 0);
        // logits bounded by 1/T=2 -> plain exp2 accumulation, no max tracking
        #pragma unroll
        for (int i = 0; i < 16; ++i)
            sums[i] += EXP2F(acc[i] * SCALE_LOG2);
    }

    // reduce each row's sum across the 32 lanes of its half (cols), then the
    // lane whose ln == reg writes that reg's row. Static indexing throughout.
    #pragma unroll
    for (int i = 0; i < 16; ++i) {
        float s = sums[i];
        #pragma unroll
        for (int off = 1; off < 32; off <<= 1) s += __shfl_xor(s, off, 64);
        if (ln == i) {
            const int rloc = (i & 3) + 8 * (i >> 2) + 4 * h;  // measured C layout
            partials[(size_t)cs * N_ROWS + row0 + rloc] = s;
        }
    }
}

// ---------- K3: merge partials + label logit + nll -> loss ----------
// block = 4 waves, 32 rows/block (grid 256); 32 lanes per row (j = lane&31 ==
// cs index); 2 rows per wave-iteration.
__global__ __launch_bounds__(256) void k_finalize(const __bf16* __restrict__ zn,
                                                  const float* __restrict__ partials,
                                                  float* __restrict__ out) {
    const int wid  = threadIdx.x >> 6;
    const int lane = threadIdx.x & 63;
    const int j    = lane & 31;            // partial-split index
    const int sub  = lane >> 5;            // 0..1: row within pair
    const int rowbase = blockIdx.x * 32 + wid * 8;
    const bf16x8* zn8 = (const bf16x8*)zn;

    float accv = 0.0f;
    #pragma unroll
    for (int it = 0; it < 4; ++it) {
        const int r = rowbase + it * 2 + sub;
        const int c = (r < B_ROWS) ? r : r - B_ROWS;   // label column
        // dot over 16 groups; lanes j and j+16 duplicate group (j&15), so the
        // 32-lane reduction yields 2*dot = (1/T)*cos = the label logit.
        bf16x8 av = zn8[(size_t)r * 16 + (j & 15)];
        bf16x8 bv = zn8[(size_t)c * 16 + (j & 15)];
        float d = 0.0f;
        #pragma unroll
        for (int e = 0; e < 8; ++e) d += (float)av[e] * (float)bv[e];
        float p = partials[(size_t)j * N_ROWS + r];
        #pragma unroll
        for (int off = 1; off < 32; off <<= 1) {
            d += __shfl_xor(d, off, 64);
            p += __shfl_xor(p, off, 64);
        }
        if (j == 0) {
            // nll = lse - logit_label = ln(row_sum) - 2*cos(r, label)
            accv += logf(p) - d;
        }
    }
    #pragma unroll
    for (int off = 1; off < 64; off <<= 1) accv += __shfl_xor(accv, off, 64);
    __shared__ float ls[4];
    if (lane == 0) ls[wid] = accv;
    __syncthreads();
    if (threadIdx.x == 0) {
        atomicAdd(out, (ls[0] + ls[1] + ls[2] + ls[3]) * (1.0f / (float)N_ROWS));
    }
}

extern "C" void kernel_launch(void* const* d_in, const int* in_sizes, int n_in,
                              void* d_out, int out_size, void* d_ws, size_t ws_size,
                              hipStream_t stream) {
    const float* zi = (const float*)d_in[0];
    const float* zj = (const float*)d_in[1];
    float* out = (float*)d_out;

    __bf16* zn       = (__bf16*)d_ws;                                      // 2 MB
    float*  partials = (float*)((char*)d_ws + (size_t)N_ROWS * D_DIM * 2); // 1 MB

    hipMemsetAsync(out, 0, sizeof(float), stream);
    k_normalize<<<dim3(N_ROWS / 4), dim3(256), 0, stream>>>(zi, zj, zn);
    k_gemm_expsum<<<dim3(64, CSPLIT), dim3(256), 0, stream>>>(zn, partials);
    k_finalize<<<dim3(N_ROWS / 32), dim3(256), 0, stream>>>(zn, partials, out);
}

// Round 3
// 47.211 us; speedup vs baseline: 1.8643x; 1.8643x over previous
//
#include <hip/hip_runtime.h>
#include <hip/hip_bf16.h>
#include <math.h>

#define B_ROWS 4096
#define N_ROWS 8192
#define D_DIM  128
// (1/T) * log2(e) = 2 * 1.4426950408889634
#define SCALE_LOG2 2.8853900817779268f
// sqrt(SCALE_LOG2): folded into row normalization so MFMA output is already
// in log2 domain (saves 16 v_mul per tile before exp2)
#define PRESCALE 1.6986436f

#define CSPLIT 32
#define CHUNK (N_ROWS / CSPLIT)        // 256 cols per block
#define TILES_PER_CHUNK (CHUNK / 32)   // 8 column tiles

typedef __bf16 bf16x8 __attribute__((ext_vector_type(8)));
typedef __bf16 bf16x2 __attribute__((ext_vector_type(2)));
typedef float  f32x16 __attribute__((ext_vector_type(16)));

#if __has_builtin(__builtin_amdgcn_exp2f)
#define EXP2F(x) __builtin_amdgcn_exp2f(x)
#else
#define EXP2F(x) exp2f(x)
#endif

// Packed fragment-major layout (16B chunk units):
//   chunk(p, kk, l) = zn[p*32 + (l&31)][ (kk*2 + (l>>5))*8 .. +8 ]   (8 bf16)
//   addr16B = p*512 + kk*64 + l
// so a wave's MFMA fragment load (any kk) is 64 consecutive 16B chunks = one
// fully coalesced 1KB transaction (vs. the 256B-strided gather it replaces).

// ---------- K1: normalize rows of concat(z_i, z_j) -> packed bf16 ----------
// one wave per row; 4 rows per 256-thread block
__global__ __launch_bounds__(256) void k_normalize(const float* __restrict__ zi,
                                                   const float* __restrict__ zj,
                                                   __bf16* __restrict__ pack) {
    const int wid  = threadIdx.x >> 6;
    const int lane = threadIdx.x & 63;
    const int row  = blockIdx.x * 4 + wid;
    const float* src = (row < B_ROWS) ? (zi + (size_t)row * D_DIM)
                                      : (zj + (size_t)(row - B_ROWS) * D_DIM);
    float2 v = ((const float2*)src)[lane];
    float ss = v.x * v.x + v.y * v.y;
    #pragma unroll
    for (int off = 1; off < 64; off <<= 1) ss += __shfl_xor(ss, off, 64);
    float inv = PRESCALE / fmaxf(sqrtf(ss), 1e-8f);
    bf16x2 o;
    o[0] = (__bf16)(v.x * inv);
    o[1] = (__bf16)(v.y * inv);
    // elements e = 2*lane, 2*lane+1 -> kk = lane>>3, h = (lane>>2)&1, m = lane&3
    const int chunk = ((row >> 5) << 9) + ((lane >> 3) << 6) +
                      (((lane >> 2) & 1) << 5) + (row & 31);
    ((bf16x2*)pack)[chunk * 4 + (lane & 3)] = o;
}

// ---------- K2: NT-GEMM (zn . zn^T) with fused exp2 row-sum ----------
// block = 4 waves; wave w owns rows [rb*128 + w*32, +32); all waves stream the
// same 256-column chunk. All fragment loads are coalesced 1KB wave loads from
// the packed layout; data is L2-resident (2MB), B tiles L1-shared across the
// block's 4 waves.
__global__ __launch_bounds__(256) void k_gemm_expsum(const __bf16* __restrict__ pack,
                                                     float* __restrict__ partials) {
    const int rb   = blockIdx.x;   // 0..63 row-block
    const int cs   = blockIdx.y;   // 0..31 column split
    const int wid  = threadIdx.x >> 6;
    const int lane = threadIdx.x & 63;
    const int h    = lane >> 5;    // lane half (k-group)
    const int ln   = lane & 31;

    const int row0 = rb * 128 + wid * 32;
    const bf16x8* pk = (const bf16x8*)pack;   // 16B chunk units

    // A fragments: coalesced — lane l reads chunk(p_row, kk, l)
    const size_t pa = (size_t)(row0 >> 5) * 512;
    bf16x8 a[8];
    #pragma unroll
    for (int kk = 0; kk < 8; ++kk)
        a[kk] = pk[pa + kk * 64 + lane];

    float sums[16];
    #pragma unroll
    for (int i = 0; i < 16; ++i) sums[i] = 0.0f;

    const int pc0 = (cs * CHUNK) >> 5;      // first column panel
    for (int ct = 0; ct < TILES_PER_CHUNK; ++ct) {
        const size_t pb = (size_t)(pc0 + ct) * 512;
        bf16x8 b[8];
        #pragma unroll
        for (int kk = 0; kk < 8; ++kk)
            b[kk] = pk[pb + kk * 64 + lane];
        f32x16 acc = {};
        #pragma unroll
        for (int kk = 0; kk < 8; ++kk)
            acc = __builtin_amdgcn_mfma_f32_32x32x16_bf16(a[kk], b[kk], acc, 0, 0, 0);
        // rows pre-scaled by sqrt(2/ln2): acc is already logit*log2e.
        // logits bounded by 1/T=2 -> plain exp2 accumulation, no max tracking
        #pragma unroll
        for (int i = 0; i < 16; ++i)
            sums[i] += EXP2F(acc[i]);
    }

    // reduce each row's sum across the 32 lanes of its half (cols), then the
    // lane whose ln == reg writes that reg's row. Static indexing throughout.
    #pragma unroll
    for (int i = 0; i < 16; ++i) {
        float s = sums[i];
        #pragma unroll
        for (int off = 1; off < 32; off <<= 1) s += __shfl_xor(s, off, 64);
        if (ln == i) {
            const int rloc = (i & 3) + 8 * (i >> 2) + 4 * h;  // measured C layout
            partials[(size_t)cs * N_ROWS + row0 + rloc] = s;
        }
    }
}

// ---------- K3: merge partials + label logit + nll -> loss ----------
// block = 4 waves, 32 rows/block (grid 256); 32 lanes per row (j = lane&31 ==
// cs index); 2 rows per wave-iteration.
__global__ __launch_bounds__(256) void k_finalize(const __bf16* __restrict__ pack,
                                                  const float* __restrict__ partials,
                                                  float* __restrict__ out) {
    const int wid  = threadIdx.x >> 6;
    const int lane = threadIdx.x & 63;
    const int j    = lane & 31;            // partial-split index
    const int sub  = lane >> 5;            // 0..1: row within pair
    const int rowbase = blockIdx.x * 32 + wid * 8;
    const bf16x8* pk = (const bf16x8*)pack;

    float accv = 0.0f;
    #pragma unroll
    for (int it = 0; it < 4; ++it) {
        const int r = rowbase + it * 2 + sub;
        const int c = (r < B_ROWS) ? r : r - B_ROWS;   // label column
        // dot over 16 groups; lanes j and j+16 duplicate group (j&15), so the
        // 32-lane reduction yields 2*PRESCALE^2*cos = 2*SCALE_LOG2*cos.
        const int g = j & 15;
        const int goff = ((g >> 1) << 6) + ((g & 1) << 5);
        bf16x8 av = pk[(size_t)(r >> 5) * 512 + goff + (r & 31)];
        bf16x8 bv = pk[(size_t)(c >> 5) * 512 + goff + (c & 31)];
        float d = 0.0f;
        #pragma unroll
        for (int e = 0; e < 8; ++e) d += (float)av[e] * (float)bv[e];
        float p = partials[(size_t)j * N_ROWS + r];
        #pragma unroll
        for (int off = 1; off < 32; off <<= 1) {
            d += __shfl_xor(d, off, 64);
            p += __shfl_xor(p, off, 64);
        }
        if (j == 0) {
            // nll = lse - logit_label = ln(row_sum) - 2*cos(r,label)
            //     = logf(p) - d / SCALE_LOG2
            accv += logf(p) - d * (1.0f / SCALE_LOG2);
        }
    }
    #pragma unroll
    for (int off = 1; off < 64; off <<= 1) accv += __shfl_xor(accv, off, 64);
    __shared__ float ls[4];
    if (lane == 0) ls[wid] = accv;
    __syncthreads();
    if (threadIdx.x == 0) {
        atomicAdd(out, (ls[0] + ls[1] + ls[2] + ls[3]) * (1.0f / (float)N_ROWS));
    }
}

extern "C" void kernel_launch(void* const* d_in, const int* in_sizes, int n_in,
                              void* d_out, int out_size, void* d_ws, size_t ws_size,
                              hipStream_t stream) {
    const float* zi = (const float*)d_in[0];
    const float* zj = (const float*)d_in[1];
    float* out = (float*)d_out;

    __bf16* pack     = (__bf16*)d_ws;                                      // 2 MB
    float*  partials = (float*)((char*)d_ws + (size_t)N_ROWS * D_DIM * 2); // 1 MB

    hipMemsetAsync(out, 0, sizeof(float), stream);
    k_normalize<<<dim3(N_ROWS / 4), dim3(256), 0, stream>>>(zi, zj, pack);
    k_gemm_expsum<<<dim3(64, CSPLIT), dim3(256), 0, stream>>>(pack, partials);
    k_finalize<<<dim3(N_ROWS / 32), dim3(256), 0, stream>>>(pack, partials, out);
}